// Round 1
// baseline (614.834 us; speedup 1.0000x reference)
//
#include <hip/hip_runtime.h>

#define NN 100000
#define NE 1600000

// ---------------- CSR build kernels ----------------

__global__ void k_count(const int* __restrict__ dst, int* __restrict__ deg) {
    int e = blockIdx.x * blockDim.x + threadIdx.x;
    if (e < NE) atomicAdd(&deg[dst[e]], 1);
}

// Block scans 1024 elements (256 threads x 4 items). Writes exclusive prefix
// into offs, block total into bsums[b].
__global__ void k_scan1(const int* __restrict__ deg, int* __restrict__ offs,
                        int* __restrict__ bsums) {
    __shared__ int ts[256];
    int b = blockIdx.x, t = threadIdx.x;
    int base = b * 1024 + t * 4;
    int v[4];
    int s = 0;
#pragma unroll
    for (int i = 0; i < 4; ++i) {
        int idx = base + i;
        v[i] = (idx < NN) ? deg[idx] : 0;
        s += v[i];
    }
    ts[t] = s;
    __syncthreads();
    for (int off = 1; off < 256; off <<= 1) {
        int x = (t >= off) ? ts[t - off] : 0;
        __syncthreads();
        ts[t] += x;
        __syncthreads();
    }
    int excl = ts[t] - s;  // exclusive prefix of this thread's first item
#pragma unroll
    for (int i = 0; i < 4; ++i) {
        int idx = base + i;
        if (idx < NN) offs[idx] = excl;
        excl += v[i];
    }
    if (t == 255) bsums[b] = ts[255];
}

__global__ void k_scan2(int* __restrict__ bsums, int nb) {
    if (threadIdx.x == 0 && blockIdx.x == 0) {
        int acc = 0;
        for (int i = 0; i < nb; ++i) {
            int v = bsums[i];
            bsums[i] = acc;
            acc += v;
        }
    }
}

__global__ void k_scan3(int* __restrict__ offs, const int* __restrict__ bsums) {
    int i = blockIdx.x * blockDim.x + threadIdx.x;
    if (i < NN) offs[i] += bsums[i >> 10];
    if (i == 0) offs[NN] = NE;
}

__global__ void k_scatter(const int* __restrict__ src, const int* __restrict__ dst,
                          const int* __restrict__ offs, int* __restrict__ cursor,
                          int* __restrict__ ssrc) {
    int e = blockIdx.x * blockDim.x + threadIdx.x;
    if (e < NE) {
        int d = dst[e];
        int p = offs[d] + atomicAdd(&cursor[d], 1);
        ssrc[p] = src[e];
    }
}

__global__ void k_deginv(const int* __restrict__ deg, float* __restrict__ dinv) {
    int i = blockIdx.x * blockDim.x + threadIdx.x;
    if (i < NN) dinv[i] = (deg[i] > 0) ? (1.0f / (float)deg[i]) : 0.0f;
}

// ---------------- fused SAGE layer ----------------
// 32 lanes own one node (feature j = lane). Gather-sum neighbor rows
// (coalesced 128B per group per edge), normalize, then combine:
// out[j] = sigmoid( sum_k hs[k]*Ws[k][j] + hn[k]*Wn[k][j] + b[j] )
// via __shfl broadcasts of hs[k], hn[k] within the 32-lane group.
template <int OUTF>
__global__ __launch_bounds__(256) void k_sage(
    const float* __restrict__ hin, const int* __restrict__ offs,
    const int* __restrict__ ssrc, const float* __restrict__ dinv,
    const float* __restrict__ Ws, const float* __restrict__ Wn,
    const float* __restrict__ bias, float* __restrict__ hout) {
    __shared__ float sWs[32 * OUTF];
    __shared__ float sWn[32 * OUTF];
    __shared__ float sB[OUTF];
    for (int i = threadIdx.x; i < 32 * OUTF; i += blockDim.x) {
        sWs[i] = Ws[i];
        sWn[i] = Wn[i];
    }
    if (threadIdx.x < OUTF) sB[threadIdx.x] = bias[threadIdx.x];
    __syncthreads();

    int g = threadIdx.x >> 5;
    int lane = threadIdx.x & 31;
    int node = blockIdx.x * 8 + g;
    if (node >= NN) return;

    float hs = hin[node * 32 + lane];
    int e0 = offs[node], e1 = offs[node + 1];
    float agg = 0.0f;
    for (int e = e0; e < e1; ++e) {
        agg += hin[ssrc[e] * 32 + lane];
    }
    float hn = agg * dinv[node];

    float acc = (lane < OUTF) ? sB[lane] : 0.0f;
#pragma unroll
    for (int k = 0; k < 32; ++k) {
        float a = __shfl(hs, k, 32);
        float n = __shfl(hn, k, 32);
        if (lane < OUTF) acc += a * sWs[k * OUTF + lane] + n * sWn[k * OUTF + lane];
    }
    if (lane < OUTF) {
        hout[node * OUTF + lane] = 1.0f / (1.0f + expf(-acc));
    }
}

// ---------------- launcher ----------------

extern "C" void kernel_launch(void* const* d_in, const int* in_sizes, int n_in,
                              void* d_out, int out_size, void* d_ws, size_t ws_size,
                              hipStream_t stream) {
    const float* inputs = (const float*)d_in[0];
    const int* src = (const int*)d_in[1];
    const int* dst = (const int*)d_in[2];
    const float* Ws1 = (const float*)d_in[3];
    const float* Wn1 = (const float*)d_in[4];
    const float* b1 = (const float*)d_in[5];
    const float* Ws2 = (const float*)d_in[6];
    const float* Wn2 = (const float*)d_in[7];
    const float* b2 = (const float*)d_in[8];
    const float* Ws3 = (const float*)d_in[9];
    const float* Wn3 = (const float*)d_in[10];
    const float* b3 = (const float*)d_in[11];
    float* out = (float*)d_out;

    int* ws = (int*)d_ws;
    int* deg = ws;                    // 100000
    int* cursor = ws + 100000;        // 100000
    int* offs = ws + 200000;          // 100001
    int* bsums = ws + 300016;         // 128
    int* ssrc = ws + 300160;          // 1600000
    float* dinv = (float*)(ws + 1900160);  // 100000
    float* h1 = (float*)(ws + 2000160);    // 3200000
    float* h2 = (float*)(ws + 5200160);    // 3200000

    // zero deg + cursor (contiguous)
    hipMemsetAsync(deg, 0, 200000 * sizeof(int), stream);

    k_count<<<NE / 256, 256, 0, stream>>>(dst, deg);
    k_scan1<<<98, 256, 0, stream>>>(deg, offs, bsums);
    k_scan2<<<1, 64, 0, stream>>>(bsums, 98);
    k_scan3<<<(NN + 255) / 256, 256, 0, stream>>>(offs, bsums);
    k_scatter<<<NE / 256, 256, 0, stream>>>(src, dst, offs, cursor, ssrc);
    k_deginv<<<(NN + 255) / 256, 256, 0, stream>>>(deg, dinv);

    k_sage<32><<<NN / 8, 256, 0, stream>>>(inputs, offs, ssrc, dinv, Ws1, Wn1, b1, h1);
    k_sage<32><<<NN / 8, 256, 0, stream>>>(h1, offs, ssrc, dinv, Ws2, Wn2, b2, h2);
    k_sage<16><<<NN / 8, 256, 0, stream>>>(h2, offs, ssrc, dinv, Ws3, Wn3, b3, out);
}